// Round 11
// baseline (316.810 us; speedup 1.0000x reference)
//
#include <hip/hip_runtime.h>

// GCN: 3 layers, dims 64->64->64->32, N=100000 nodes, E=1600000 edges.
// Round 11:
//  - fused agg+gemm: Ws staged as fp16 (8KB) -> LDS 25->16.5KB, launch_bounds
//    (256,8) => 8 blocks/CU (was 54% occupancy). Probes whether the 53us
//    gather plateau is concurrency-limited or XCD->L3 fabric-limited
//    (R7/R9/R10 all ~2.9-3.3 TB/s on ~156MB L2-miss traffic).
//  - CSR build: wave-private chunks (2048 edges/wave) with per-wave LDS
//    hists + cursors in pass A, and wave-private hist + per-(node,wave)
//    placement cursors in pass B. Removes intra-block LDS atomic contention.
// fp16 storage between layers, fp32 accumulation; zero global atomics.

typedef __attribute__((ext_vector_type(8))) _Float16 half8;
typedef __attribute__((ext_vector_type(4))) _Float16 half4;

static inline int cdiv(int a, int b) { return (a + b - 1) / b; }

#define CHW 2048      // edges per WAVE chunk (pass A)
#define MAXNBK 512    // max buckets (N <= 131072)

// ---- pass A1: per-wave bucket histogram -> counts_t[bucket*NW + chunk]
__global__ void k_bucket_hist(const int* __restrict__ dst, int* __restrict__ counts_t,
                              int NBK, int NW, int E) {
    __shared__ int cnt[4][MAXNBK];
    int t = threadIdx.x, b = blockIdx.x;
    int w = t >> 6, lane = t & 63;
    for (int i = t; i < 4 * MAXNBK; i += 256) ((int*)cnt)[i] = 0;
    __syncthreads();
    int c = b * 4 + w;
    if (c < NW) {
        int e0 = c * CHW;
#pragma unroll 8
        for (int j = 0; j < CHW / 64; ++j) {
            int e = e0 + j * 64 + lane;
            if (e < E) atomicAdd(&cnt[w][dst[e] >> 8], 1);
        }
    }
    __syncthreads();
    for (int i = t; i < NBK; i += 256) {
#pragma unroll
        for (int ww = 0; ww < 4; ++ww) {
            int cc = b * 4 + ww;
            if (cc < NW) counts_t[i * NW + cc] = cnt[ww][i];
        }
    }
}

// ---- hierarchical exclusive scan over a[0..n): partial + (bsum-scan fused final)
#define SCAN_T 256
#define SCAN_V 8
#define SCAN_CHUNK 2048

__global__ void k_scan_partial(const int* __restrict__ a, int* __restrict__ bsum, int n) {
    __shared__ int red[SCAN_T];
    int t = threadIdx.x, b = blockIdx.x;
    int base = b * SCAN_CHUNK + t * SCAN_V;
    int s = 0;
#pragma unroll
    for (int j = 0; j < SCAN_V; ++j) { int i = base + j; if (i < n) s += a[i]; }
    red[t] = s;
    __syncthreads();
    for (int off = SCAN_T / 2; off > 0; off >>= 1) {
        if (t < off) red[t] += red[t + off];
        __syncthreads();
    }
    if (t == 0) bsum[b] = red[0];
}

// nb <= 256. Every block redundantly scans bsum in LDS, picks its base.
__global__ void k_scan_final(const int* __restrict__ a, const int* __restrict__ bsum,
                             int* __restrict__ out, int nb, int n) {
    __shared__ int sb[256];
    __shared__ int sh[SCAN_T];
    int t = threadIdx.x, bk = blockIdx.x;
    sb[t] = (t < nb) ? bsum[t] : 0;
    __syncthreads();
    for (int off = 1; off < 256; off <<= 1) {
        int u = (t >= off) ? sb[t - off] : 0;
        __syncthreads();
        sb[t] += u;
        __syncthreads();
    }
    int bbase = (bk == 0) ? 0 : sb[bk - 1];
    int base = bk * SCAN_CHUNK + t * SCAN_V;
    int v[SCAN_V];
    int s = 0;
#pragma unroll
    for (int j = 0; j < SCAN_V; ++j) {
        int i = base + j;
        v[j] = (i < n) ? a[i] : 0;
        s += v[j];
    }
    sh[t] = s;
    __syncthreads();
    for (int off = 1; off < SCAN_T; off <<= 1) {
        int u = (t >= off) ? sh[t - off] : 0;
        __syncthreads();
        sh[t] += u;
        __syncthreads();
    }
    int run = sh[t] - s + bbase;
#pragma unroll
    for (int j = 0; j < SCAN_V; ++j) {
        int i = base + j;
        if (i < n) { out[i] = run; run += v[j]; }
    }
}

// ---- pass A3: scatter edges into bucket regions via per-wave LDS cursors.
// packed word: src (24 bits) | (dst & 255) << 24.
__global__ void k_bucket_scatter(const int* __restrict__ src, const int* __restrict__ dst,
                                 const int* __restrict__ offsets, unsigned* __restrict__ bucketed,
                                 int NBK, int NW, int E) {
    __shared__ int curs[4][MAXNBK];
    int t = threadIdx.x, b = blockIdx.x;
    int w = t >> 6, lane = t & 63;
    for (int i = t; i < NBK; i += 256) {
#pragma unroll
        for (int ww = 0; ww < 4; ++ww) {
            int cc = b * 4 + ww;
            if (cc < NW) curs[ww][i] = offsets[i * NW + cc];
        }
    }
    __syncthreads();
    int c = b * 4 + w;
    if (c >= NW) return;
    int e0 = c * CHW;
#pragma unroll 8
    for (int j = 0; j < CHW / 64; ++j) {
        int e = e0 + j * 64 + lane;
        if (e < E) {
            int d = dst[e];
            int pos = atomicAdd(&curs[w][d >> 8], 1);
            bucketed[pos] = (unsigned)src[e] | ((unsigned)(d & 255) << 24);
        }
    }
}

// ---- pass B: one block per bucket. Wave-private LDS hist over 256 nodes ->
// LDS scan -> per-(node,wave) cursors -> emit csr_src, row_start, dis.
__global__ void k_bucket_build(const unsigned* __restrict__ bucketed,
                               const int* __restrict__ offsets,
                               int* __restrict__ csr_src, int* __restrict__ row_start,
                               float* __restrict__ dis, int NBK, int NW, int N, int E) {
    __shared__ int cnt4[4][256];
    __shared__ int sc[256];
    int t = threadIdx.x, k = blockIdx.x;
    int w = t >> 6, lane = t & 63;
    int base = offsets[k * NW];
    int end = (k + 1 < NBK) ? offsets[(k + 1) * NW] : E;
#pragma unroll
    for (int ww = 0; ww < 4; ++ww) cnt4[ww][t] = 0;
    __syncthreads();
    for (int i = base + w * 64 + lane; i < end; i += 256)
        atomicAdd(&cnt4[w][bucketed[i] >> 24], 1);
    __syncthreads();
    int c0 = cnt4[0][t], c1 = cnt4[1][t], c2 = cnt4[2][t], c3 = cnt4[3][t];
    int c = c0 + c1 + c2 + c3;
    sc[t] = c;
    __syncthreads();
    for (int off = 1; off < 256; off <<= 1) {
        int u = (t >= off) ? sc[t - off] : 0;
        __syncthreads();
        sc[t] += u;
        __syncthreads();
    }
    int excl = sc[t] - c;
    int node = k * 256 + t;
    if (node < N) {
        row_start[node] = base + excl;
        dis[node] = rsqrtf(1.0f + (float)c);
    }
    if (k == 0 && t == 0) row_start[N] = E;
    // per-(node,wave) placement cursors (atomic-free across waves)
    int b0 = base + excl;
    cnt4[0][t] = b0;
    cnt4[1][t] = b0 + c0;
    cnt4[2][t] = b0 + c0 + c1;
    cnt4[3][t] = b0 + c0 + c1 + c2;
    __syncthreads();
    for (int i = base + w * 64 + lane; i < end; i += 256) {
        unsigned v = bucketed[i];
        int pos = atomicAdd(&cnt4[w][v >> 24], 1);
        csr_src[pos] = (int)(v & 0xFFFFFFu);
    }
}

// ---- fp32-input GEMM (layer 1): H = fp16((X@W) * dis[row]), 8 outs/thread
template <int K, int M>
__global__ void k_gemm_f(const float* __restrict__ X, const float* __restrict__ W,
                         const float* __restrict__ dis, _Float16* __restrict__ H, int n) {
    constexpr int TPR = M / 8;
    constexpr int ROWS = 256 / TPR;
    constexpr int KP = K + 1;
    __shared__ float Ws[K * M];
    __shared__ float Xs[ROWS * KP];
    int tid = threadIdx.x;
    for (int idx = tid; idx < K * M / 4; idx += 256)
        ((float4*)Ws)[idx] = ((const float4*)W)[idx];
    int row0 = blockIdx.x * ROWS;
    for (int idx = tid; idx < ROWS * (K / 4); idx += 256) {
        int r = idx / (K / 4), kq = idx % (K / 4);
        int row = row0 + r;
        float4 vv = (row < n) ? ((const float4*)X)[(size_t)row * (K / 4) + kq]
                              : make_float4(0.f, 0.f, 0.f, 0.f);
        Xs[r * KP + kq * 4 + 0] = vv.x;
        Xs[r * KP + kq * 4 + 1] = vv.y;
        Xs[r * KP + kq * 4 + 2] = vv.z;
        Xs[r * KP + kq * 4 + 3] = vv.w;
    }
    __syncthreads();
    int r = tid / TPR, c0 = (tid % TPR) * 8;
    int row = row0 + r;
    if (row >= n) return;
    float4 a0 = make_float4(0.f, 0.f, 0.f, 0.f);
    float4 a1 = make_float4(0.f, 0.f, 0.f, 0.f);
#pragma unroll
    for (int k = 0; k < K; ++k) {
        float xv = Xs[r * KP + k];
        float4 w0 = ((const float4*)Ws)[(k * M + c0) / 4];
        float4 w1 = ((const float4*)Ws)[(k * M + c0) / 4 + 1];
        a0.x = fmaf(xv, w0.x, a0.x);
        a0.y = fmaf(xv, w0.y, a0.y);
        a0.z = fmaf(xv, w0.z, a0.z);
        a0.w = fmaf(xv, w0.w, a0.w);
        a1.x = fmaf(xv, w1.x, a1.x);
        a1.y = fmaf(xv, w1.y, a1.y);
        a1.z = fmaf(xv, w1.z, a1.z);
        a1.w = fmaf(xv, w1.w, a1.w);
    }
    float dn = dis[row];
    half8 hv;
    hv[0] = (_Float16)(a0.x * dn);
    hv[1] = (_Float16)(a0.y * dn);
    hv[2] = (_Float16)(a0.z * dn);
    hv[3] = (_Float16)(a0.w * dn);
    hv[4] = (_Float16)(a1.x * dn);
    hv[5] = (_Float16)(a1.y * dn);
    hv[6] = (_Float16)(a1.z * dn);
    hv[7] = (_Float16)(a1.w * dn);
    ((half8*)H)[(size_t)row * (M / 8) + c0 / 8] = hv;
}

// ---- FUSED: aggregate(64) [+relu] -> LDS -> GEMM(64 x MOUT) -> h' fp16.
// 32 nodes/block (4 waves x 8 nodes, lane-per-8-features, 4-edge unroll).
// Ws staged fp16 (8KB) -> total LDS ~16.5KB -> 8 blocks/CU.
template <int MOUT>
__global__ __launch_bounds__(256, 8)
void k_fused_agg_gemm(const _Float16* __restrict__ h, const float* __restrict__ dis,
                      const int* __restrict__ row_start, const int* __restrict__ csr_src,
                      const float* __restrict__ bagg, const float* __restrict__ W,
                      _Float16* __restrict__ H, int n) {
    constexpr int K = 64, KP = K + 1;
    __shared__ _Float16 Ws[K * MOUT];
    __shared__ float Xs[32 * KP];
    int tid = threadIdx.x;
    // stage W fp32 -> fp16
    for (int idx = tid; idx < K * MOUT / 4; idx += 256) {
        float4 v = ((const float4*)W)[idx];
        half4 hh;
        hh[0] = (_Float16)v.x;
        hh[1] = (_Float16)v.y;
        hh[2] = (_Float16)v.z;
        hh[3] = (_Float16)v.w;
        ((half4*)Ws)[idx] = hh;
    }

    // ---- aggregate phase ----
    int wave = tid >> 6, lane = tid & 63;
    int sub = lane >> 3, fl = lane & 7;
    int node0 = blockIdx.x * 32;
    int node = node0 + wave * 8 + sub;
    if (node < n) {
        const half8* h8 = (const half8*)h;
        float acc[8];
#pragma unroll
        for (int j = 0; j < 8; ++j) acc[j] = 0.f;
        int e = row_start[node], e1 = row_start[node + 1];
        for (; e + 3 < e1; e += 4) {
            int s0 = csr_src[e], s1 = csr_src[e + 1];
            int s2 = csr_src[e + 2], s3 = csr_src[e + 3];
            half8 v0 = h8[(size_t)s0 * 8 + fl];
            half8 v1 = h8[(size_t)s1 * 8 + fl];
            half8 v2 = h8[(size_t)s2 * 8 + fl];
            half8 v3 = h8[(size_t)s3 * 8 + fl];
#pragma unroll
            for (int j = 0; j < 8; ++j)
                acc[j] += ((float)v0[j] + (float)v1[j]) + ((float)v2[j] + (float)v3[j]);
        }
        for (; e < e1; ++e) {
            int s0 = csr_src[e];
            half8 v0 = h8[(size_t)s0 * 8 + fl];
#pragma unroll
            for (int j = 0; j < 8; ++j) acc[j] += (float)v0[j];
        }
        float dn = dis[node];
        half8 hv = h8[(size_t)node * 8 + fl];
        float4 b0 = ((const float4*)bagg)[fl * 2];
        float4 b1 = ((const float4*)bagg)[fl * 2 + 1];
        int rrow = wave * 8 + sub;
        float* xp = &Xs[rrow * KP + fl * 8];
        xp[0] = fmaxf((acc[0] + (float)hv[0]) * dn + b0.x, 0.f);
        xp[1] = fmaxf((acc[1] + (float)hv[1]) * dn + b0.y, 0.f);
        xp[2] = fmaxf((acc[2] + (float)hv[2]) * dn + b0.z, 0.f);
        xp[3] = fmaxf((acc[3] + (float)hv[3]) * dn + b0.w, 0.f);
        xp[4] = fmaxf((acc[4] + (float)hv[4]) * dn + b1.x, 0.f);
        xp[5] = fmaxf((acc[5] + (float)hv[5]) * dn + b1.y, 0.f);
        xp[6] = fmaxf((acc[6] + (float)hv[6]) * dn + b1.z, 0.f);
        xp[7] = fmaxf((acc[7] + (float)hv[7]) * dn + b1.w, 0.f);
    }
    __syncthreads();

    // ---- gemm phase: 32 rows x MOUT cols, 8 cols/thread, fp16 W ----
    constexpr int TPR = MOUT / 8;
    int r = tid / TPR, c0 = (tid % TPR) * 8;
    int row = node0 + r;
    if (r >= 32 || row >= n) return;
    float a[8];
#pragma unroll
    for (int j = 0; j < 8; ++j) a[j] = 0.f;
#pragma unroll
    for (int k = 0; k < K; ++k) {
        float xv = Xs[r * KP + k];
        half8 wv = ((const half8*)Ws)[k * (MOUT / 8) + c0 / 8];
#pragma unroll
        for (int j = 0; j < 8; ++j) a[j] = fmaf(xv, (float)wv[j], a[j]);
    }
    float dn = dis[row];
    half8 hv;
#pragma unroll
    for (int j = 0; j < 8; ++j) hv[j] = (_Float16)(a[j] * dn);
    ((half8*)H)[(size_t)row * (MOUT / 8) + c0 / 8] = hv;
}

// ---- final aggregate: M=32, fp32 out, no relu. lane-per-8-features,
// LPN=4, NPW=16, 4-edge unroll.
__global__ void k_aggregate32(const _Float16* __restrict__ h, const float* __restrict__ dis,
                              const int* __restrict__ row_start, const int* __restrict__ csr_src,
                              const float* __restrict__ b, float* __restrict__ out, int n) {
    constexpr int LPN = 4, NPW = 16;
    int gtid = blockIdx.x * blockDim.x + threadIdx.x;
    int wave = gtid >> 6;
    int lane = threadIdx.x & 63;
    int sub = lane / LPN, fl = lane % LPN;
    int node = wave * NPW + sub;
    if (node >= n) return;
    const half8* h8 = (const half8*)h;
    float acc[8];
#pragma unroll
    for (int j = 0; j < 8; ++j) acc[j] = 0.f;
    int e = row_start[node], e1 = row_start[node + 1];
    for (; e + 3 < e1; e += 4) {
        int s0 = csr_src[e], s1 = csr_src[e + 1];
        int s2 = csr_src[e + 2], s3 = csr_src[e + 3];
        half8 v0 = h8[(size_t)s0 * LPN + fl];
        half8 v1 = h8[(size_t)s1 * LPN + fl];
        half8 v2 = h8[(size_t)s2 * LPN + fl];
        half8 v3 = h8[(size_t)s3 * LPN + fl];
#pragma unroll
        for (int j = 0; j < 8; ++j)
            acc[j] += ((float)v0[j] + (float)v1[j]) + ((float)v2[j] + (float)v3[j]);
    }
    for (; e < e1; ++e) {
        int s0 = csr_src[e];
        half8 v0 = h8[(size_t)s0 * LPN + fl];
#pragma unroll
        for (int j = 0; j < 8; ++j) acc[j] += (float)v0[j];
    }
    float dn = dis[node];
    half8 hv = h8[(size_t)node * LPN + fl];
    float4 b0 = ((const float4*)b)[fl * 2];
    float4 b1 = ((const float4*)b)[fl * 2 + 1];
    float4* op = (float4*)(out + ((size_t)node * LPN + fl) * 8);
    op[0] = make_float4((acc[0] + (float)hv[0]) * dn + b0.x,
                        (acc[1] + (float)hv[1]) * dn + b0.y,
                        (acc[2] + (float)hv[2]) * dn + b0.z,
                        (acc[3] + (float)hv[3]) * dn + b0.w);
    op[1] = make_float4((acc[4] + (float)hv[4]) * dn + b1.x,
                        (acc[5] + (float)hv[5]) * dn + b1.y,
                        (acc[6] + (float)hv[6]) * dn + b1.z,
                        (acc[7] + (float)hv[7]) * dn + b1.w);
}

extern "C" void kernel_launch(void* const* d_in, const int* in_sizes, int n_in,
                              void* d_out, int out_size, void* d_ws, size_t ws_size,
                              hipStream_t stream) {
    const float* x   = (const float*)d_in[0];
    const int*   ei  = (const int*)d_in[1];
    const float* W1  = (const float*)d_in[2];
    const float* b1  = (const float*)d_in[3];
    const float* W2  = (const float*)d_in[4];
    const float* b2  = (const float*)d_in[5];
    const float* W3  = (const float*)d_in[6];
    const float* b3  = (const float*)d_in[7];
    float* out = (float*)d_out;

    const int N = in_sizes[0] / 64;
    const int E = in_sizes[1] / 2;
    const int* src = ei;
    const int* dst = ei + E;

    const int NBK = cdiv(N, 256);   // 391 buckets of 256 nodes
    const int NW  = cdiv(E, CHW);   // 782 wave-chunks
    const int NBA = cdiv(NW, 4);    // 196 pass-A blocks
    const int nmat = NBK * NW;      // 305762 scan elements

    // workspace layout
    const size_t Np = (size_t)((N + 63) / 64) * 64;
    char* p = (char*)d_ws;
    int*      counts_t = (int*)p;      p += (size_t)nmat * sizeof(int);
    int*      offsets  = (int*)p;      p += (size_t)nmat * sizeof(int);
    int*      bsum     = (int*)p;      p += 1024 * sizeof(int);
    int*      row_start= (int*)p;      p += (Np + 64) * sizeof(int);
    float*    dis      = (float*)p;    p += Np * sizeof(float);
    unsigned* bucketed = (unsigned*)p; p += (size_t)E * sizeof(unsigned);
    int*      csr_src  = (int*)p;      p += (size_t)E * sizeof(int);
    _Float16* bufA     = (_Float16*)p; p += Np * 64 * sizeof(_Float16);
    _Float16* bufB     = (_Float16*)p; p += Np * 64 * sizeof(_Float16);
    (void)ws_size;

    const int B = 256;
    const int nb = cdiv(nmat, SCAN_CHUNK);  // 150 <= 256

    // ---- CSR build: LDS counting sort, no global atomics ----
    k_bucket_hist<<<NBA, B, 0, stream>>>(dst, counts_t, NBK, NW, E);
    k_scan_partial<<<nb, B, 0, stream>>>(counts_t, bsum, nmat);
    k_scan_final<<<nb, B, 0, stream>>>(counts_t, bsum, offsets, nb, nmat);
    k_bucket_scatter<<<NBA, B, 0, stream>>>(src, dst, offsets, bucketed, NBK, NW, E);
    k_bucket_build<<<NBK, B, 0, stream>>>(bucketed, offsets, csr_src, row_start, dis,
                                          NBK, NW, N, E);

    // ---- layer 1 gemm: x(64) @ W1 -> h1 (bufA) ----
    k_gemm_f<64, 64><<<cdiv(N, 32), B, 0, stream>>>(x, W1, dis, bufA, N);
    // ---- fused: agg(h1)+relu -> gemm W2 -> h2 (bufB) ----
    k_fused_agg_gemm<64><<<cdiv(N, 32), B, 0, stream>>>(
        bufA, dis, row_start, csr_src, b1, W2, bufB, N);
    // ---- fused: agg(h2)+relu -> gemm W3 -> h3 (bufA, 32-dim) ----
    k_fused_agg_gemm<32><<<cdiv(N, 32), B, 0, stream>>>(
        bufB, dis, row_start, csr_src, b2, W3, bufA, N);
    // ---- final aggregate: agg(h3) + b3 -> out (fp32) ----
    k_aggregate32<<<cdiv(cdiv(N, 16) * 64, B), B, 0, stream>>>(
        bufA, dis, row_start, csr_src, b3, out, N);
}